// Round 9
// baseline (491.544 us; speedup 1.0000x reference)
//
#include <hip/hip_runtime.h>

// GraphSAGE: 3x SAGEConv(mean) + linear head.
// N=100000 nodes, E=3200000 edges, dims 64 -> 64 -> 32 -> 16 -> 1.
// Round 9 = round 8 with the CSR build restructured:
//  - part1_k: fused hist + block-local scan + place. pair is BLOCK-MAJOR:
//    each block writes its own contiguous chunk (write amp ~= 1 by
//    construction; round-8 scatter_pack had 5x amp from 64B unaligned
//    bucket-major regions shared across XCDs).
//  - count/offset tables written c-major (contiguous per block), then a
//    32x32 LDS transpose -> i-major for the bucket-major scan.
//  - sort_bucket_k reads 256 slices (one per thread, ~8 contiguous edges,
//    L1-resident across its 2 passes); adj/off/inv writes unchanged
//    (block-exclusive contiguous).
//  - layers unchanged: transform2 (g=h@Wl bf16, r=h@Wr+b), pull agg_k.
// agg-linearity: mean(h[src]) @ Wl == mean((h@Wl)[src]) -> transform first.

#define NN 100000
#define BSH 6                       // bucket = dst >> 6 (64 nodes)
#define NBK ((NN + 63) >> 6)        // 1563 buckets
#define HB 256                      // partition blocks / slices per bucket
#define SRCMASK 0x1FFFF             // 17 bits, N=100000 < 2^17
#define NSEG 8192                   // scan segments
#define SCB 32                      // scan blocks (NSEG/256)

__device__ __forceinline__ unsigned f2bf(float f) {   // RNE fp32->bf16
    unsigned u = __float_as_uint(f);
    u += 0x7fffu + ((u >> 16) & 1u);
    return u >> 16;
}
__device__ __forceinline__ float bflo(unsigned u) { return __uint_as_float(u << 16); }
__device__ __forceinline__ float bfhi(unsigned u) { return __uint_as_float(u & 0xffff0000u); }

// ---- fused: per-chunk bucket histogram + local scan + grouped place ----
// Block c owns edges [b0,e0) and pair slots [b0,e0) (block-major => all
// pair writes contiguous & block-exclusive). Tables written c-major.
__global__ void part1_k(const int* __restrict__ src, const int* __restrict__ dst,
                        int E, int* __restrict__ ghT, int* __restrict__ gh2T,
                        unsigned* __restrict__ pair) {
    __shared__ int lh[NBK];
    __shared__ int part[512];
    int c = blockIdx.x, tid = threadIdx.x;
    int chunk = (E + HB - 1) / HB;
    int b0 = c * chunk, e0 = min(b0 + chunk, E);
    for (int i = tid; i < NBK; i += 512) lh[i] = 0;
    __syncthreads();
    for (int e = b0 + tid; e < e0; e += 512) atomicAdd(&lh[dst[e] >> BSH], 1);
    __syncthreads();
    // block-wide exclusive scan of lh[0..NBK)
    constexpr int CPT = (NBK + 511) / 512;   // 4
    int myb = tid * CPT;
    int s = 0;
#pragma unroll
    for (int k = 0; k < CPT; ++k) { int i = myb + k; if (i < NBK) s += lh[i]; }
    part[tid] = s;
    __syncthreads();
    for (int d = 1; d < 512; d <<= 1) {
        int t = (tid >= d) ? part[tid - d] : 0;
        __syncthreads();
        part[tid] += t;
        __syncthreads();
    }
    int run = (tid == 0) ? 0 : part[tid - 1];
#pragma unroll
    for (int k = 0; k < CPT; ++k) {
        int i = myb + k;
        if (i < NBK) {
            int cc = lh[i];
            ghT[(size_t)c * NBK + i] = cc;    // counts, c-major (contiguous)
            gh2T[(size_t)c * NBK + i] = run;  // local offsets, c-major
            lh[i] = run;                      // becomes cursor
            run += cc;
        }
    }
    __syncthreads();
    for (int e = b0 + tid; e < e0; e += 512) {
        int dv = dst[e], sv = src[e];
        int p = b0 + atomicAdd(&lh[dv >> BSH], 1);
        pair[p] = (unsigned)sv | ((unsigned)(dv & 63) << 17);
    }
}

// ---- transpose [HB][NBK] (c-major) -> [NBK][HB] (i-major), both arrays ----
__global__ void transpose_k(const int* __restrict__ a, const int* __restrict__ b,
                            int* __restrict__ at, int* __restrict__ bt) {
    __shared__ int ta[32][33], tb[32][33];
    int ib = blockIdx.x * 32;    // i tile (NBK dim)
    int cb = blockIdx.y * 32;    // c tile (HB dim)
    int tx = threadIdx.x & 31, ty = threadIdx.x >> 5;   // 32x8
#pragma unroll
    for (int k = 0; k < 32; k += 8) {
        int c = cb + ty + k, i = ib + tx;
        if (c < HB && i < NBK) {
            ta[ty + k][tx] = a[(size_t)c * NBK + i];
            tb[ty + k][tx] = b[(size_t)c * NBK + i];
        }
    }
    __syncthreads();
#pragma unroll
    for (int k = 0; k < 32; k += 8) {
        int i = ib + ty + k, c = cb + tx;
        if (i < NBK && c < HB) {
            at[(size_t)i * HB + c] = ta[tx][ty + k];
            bt[(size_t)i * HB + c] = tb[tx][ty + k];
        }
    }
}

// ---- 3-phase parallel exclusive scan over ghm[0..M) (bucket-major) ----
__global__ void scanA_k(const int* __restrict__ gh, int M, int* __restrict__ segsum) {
    int t = blockIdx.x * blockDim.x + threadIdx.x;
    int cht = (M + NSEG - 1) / NSEG;
    int b0 = t * cht, e0 = min(b0 + cht, M);
    int s = 0;
    for (int i = b0; i < e0; ++i) s += gh[i];
    segsum[t] = s;
}

__global__ void scanB_k(int* __restrict__ segsum) {
    __shared__ int part[1024];
    int tid = threadIdx.x;
    constexpr int SPT = NSEG / 1024;
    int loc[SPT];
    int s = 0;
#pragma unroll
    for (int k = 0; k < SPT; ++k) { loc[k] = segsum[tid * SPT + k]; s += loc[k]; }
    part[tid] = s;
    __syncthreads();
    for (int d = 1; d < 1024; d <<= 1) {
        int t = (tid >= d) ? part[tid - d] : 0;
        __syncthreads();
        part[tid] += t;
        __syncthreads();
    }
    int run = (tid == 0) ? 0 : part[tid - 1];
#pragma unroll
    for (int k = 0; k < SPT; ++k) { int t = loc[k]; segsum[tid * SPT + k] = run; run += t; }
}

__global__ void scanC_k(int* __restrict__ gh, int M, const int* __restrict__ segsum) {
    int t = blockIdx.x * blockDim.x + threadIdx.x;
    int cht = (M + NSEG - 1) / NSEG;
    int b0 = t * cht, e0 = min(b0 + cht, M);
    int run = segsum[t];
    for (int i = b0; i < e0; ++i) {
        int v = gh[i];
        gh[i] = run;
        run += v;
    }
}

// ---- per-bucket counting sort -> per-node CSR (adj, off, inv) ----
// One slice per thread (HB slices); slices are tiny contiguous runs that
// stay L1-resident across the 2 passes. adj writes block-exclusive.
__global__ void sort_bucket_k(const unsigned* __restrict__ pair,
                              const int* __restrict__ ghm, const int* __restrict__ gh2m,
                              int* __restrict__ adj, int* __restrict__ off,
                              float* __restrict__ inv, int N, int E) {
    __shared__ int lcnt[64];
    __shared__ int lbase[64];
    int b = blockIdx.x, tid = threadIdx.x;
    int base = ghm[b * HB];
    int v0 = b << BSH;
    int nv = min(64, N - v0);
    if (tid < 64) lcnt[tid] = 0;
    __syncthreads();
    int chunk = (E + HB - 1) / HB;
    int c = tid;                       // blockDim == HB
    int b0c = c * chunk, e0c = min(b0c + chunk, E);
    int ls = b0c + gh2m[b * HB + c];
    int le = (b == NBK - 1) ? e0c : (b0c + gh2m[(b + 1) * HB + c]);
    for (int i = ls; i < le; ++i) atomicAdd(&lcnt[pair[i] >> 17], 1);
    __syncthreads();
    if (tid == 0) {
        int run = 0;
        for (int d = 0; d < 64; ++d) { lbase[d] = run; run += lcnt[d]; }
    }
    __syncthreads();
    if (tid < nv) {
        off[v0 + tid] = base + lbase[tid];
        inv[v0 + tid] = 1.0f / (float)max(lcnt[tid], 1);
    }
    if (b == NBK - 1 && tid == 0) off[N] = E;
    if (tid < 64) lcnt[tid] = lbase[tid];   // reuse as cursors
    __syncthreads();
    for (int i = ls; i < le; ++i) {
        unsigned u = pair[i];
        int p = base + atomicAdd(&lcnt[u >> 17], 1);
        adj[p] = u & SRCMASK;
    }
}

// ---- transform2: g = h@Wl (bf16 packed), r = h@Wr + b (fp32) ----
// node-paired (2 nodes, 2 channels per thread) so LDS-read:FMA <= 2B/FMA.
template <int DIN, int DOUT>
__global__ void transform2_k(const float* __restrict__ h,
                             const float* __restrict__ Wl, const float* __restrict__ Wr,
                             const float* __restrict__ bias,
                             unsigned* __restrict__ g, float2* __restrict__ r, int N) {
    constexpr int JP = DOUT / 2;
    __shared__ float2 sWl[DIN * JP];
    __shared__ float2 sWr[DIN * JP];
    __shared__ float2 sb[JP];
    const float2* Wl2 = (const float2*)Wl;
    const float2* Wr2 = (const float2*)Wr;
    for (int i = threadIdx.x; i < DIN * JP; i += blockDim.x) { sWl[i] = Wl2[i]; sWr[i] = Wr2[i]; }
    if (threadIdx.x < JP) sb[threadIdx.x] = ((const float2*)bias)[threadIdx.x];
    __syncthreads();
    int idx = blockIdx.x * blockDim.x + threadIdx.x;
    int NP = N / 2;                    // N even
    if (idx >= NP * JP) return;
    int p = idx / JP, jp = idx % JP;
    int v0 = 2 * p, v1 = v0 + 1;
    const float* h0 = h + (size_t)v0 * DIN;
    const float* h1 = h + (size_t)v1 * DIN;
    float gl0x = 0, gl0y = 0, gl1x = 0, gl1y = 0;
    float gr0x = 0, gr0y = 0, gr1x = 0, gr1y = 0;
#pragma unroll
    for (int k = 0; k < DIN; ++k) {
        float2 wl = sWl[k * JP + jp];
        float2 wr = sWr[k * JP + jp];
        float a0 = h0[k], a1 = h1[k];
        gl0x = fmaf(a0, wl.x, gl0x); gl0y = fmaf(a0, wl.y, gl0y);
        gl1x = fmaf(a1, wl.x, gl1x); gl1y = fmaf(a1, wl.y, gl1y);
        gr0x = fmaf(a0, wr.x, gr0x); gr0y = fmaf(a0, wr.y, gr0y);
        gr1x = fmaf(a1, wr.x, gr1x); gr1y = fmaf(a1, wr.y, gr1y);
    }
    float2 bb = sb[jp];
    g[(size_t)v0 * JP + jp] = f2bf(gl0x) | (f2bf(gl0y) << 16);
    g[(size_t)v1 * JP + jp] = f2bf(gl1x) | (f2bf(gl1y) << 16);
    r[(size_t)v0 * JP + jp] = make_float2(gr0x + bb.x, gr0y + bb.y);
    r[(size_t)v1 * JP + jp] = make_float2(gr1x + bb.x, gr1y + bb.y);
}

// ---- agg: out = relu( mean-gather(g_bf16) + r ); optional fused head ----
// One wave per dst node (PULL). Q8 = DOUT/8 lanes x uint4 (8 bf16) per row;
// EPT = 64/Q8 edge groups, 4x unroll. NOTE: out may alias r (in-place).
template <int DOUT, int WAVES, int HEAD>
__global__ void agg_k(const unsigned* __restrict__ g, const int* __restrict__ off,
                      const int* __restrict__ adj, const float* __restrict__ invc,
                      const float* r, const float* __restrict__ Wc,
                      const float* __restrict__ bc, float* out, int N) {
    constexpr int Q8 = DOUT / 8;
    constexpr int EPT = 64 / Q8;
    __shared__ float sagg[WAVES][DOUT];
    int wid = threadIdx.x >> 6, lane = threadIdx.x & 63;
    int v = blockIdx.x * WAVES + wid;
    bool active = v < N;
    int q = lane & (Q8 - 1);
    int eg = lane / Q8;
    float acc[8] = {0, 0, 0, 0, 0, 0, 0, 0};
#define ACCU(U) do { \
        acc[0] += bflo(U.x); acc[1] += bfhi(U.x); \
        acc[2] += bflo(U.y); acc[3] += bfhi(U.y); \
        acc[4] += bflo(U.z); acc[5] += bfhi(U.z); \
        acc[6] += bflo(U.w); acc[7] += bfhi(U.w); } while (0)
    if (active) {
        int beg = off[v], end = off[v + 1];
        const uint4* g4 = (const uint4*)g;   // row = Q8 uint4s
        int i = beg + eg;
        for (; i + 3 * EPT < end; i += 4 * EPT) {
            int s0 = adj[i], s1 = adj[i + EPT], s2 = adj[i + 2 * EPT], s3 = adj[i + 3 * EPT];
            uint4 u0 = g4[(size_t)s0 * Q8 + q];
            uint4 u1 = g4[(size_t)s1 * Q8 + q];
            uint4 u2 = g4[(size_t)s2 * Q8 + q];
            uint4 u3 = g4[(size_t)s3 * Q8 + q];
            ACCU(u0); ACCU(u1); ACCU(u2); ACCU(u3);
        }
        for (; i < end; i += EPT) {
            int sv = adj[i];
            uint4 u = g4[(size_t)sv * Q8 + q];
            ACCU(u);
        }
#pragma unroll
        for (int d = Q8; d < 64; d <<= 1)
#pragma unroll
            for (int c = 0; c < 8; ++c) acc[c] += __shfl_xor(acc[c], d, 64);
        if (eg == 0) {
            float4* sp = (float4*)&sagg[wid][q * 8];
            sp[0] = make_float4(acc[0], acc[1], acc[2], acc[3]);
            sp[1] = make_float4(acc[4], acc[5], acc[6], acc[7]);
        }
    }
#undef ACCU
    __syncthreads();
    if (active && lane < DOUT) {
        float iv = invc[v];
        float val = fmaxf(fmaf(sagg[wid][lane], iv, r[(size_t)v * DOUT + lane]), 0.f);
        if (!HEAD) {
            out[(size_t)v * DOUT + lane] = val;   // may alias r: read-before-write per thread
        } else {
            float pp = val * Wc[lane];
#pragma unroll
            for (int d = 1; d < 16; d <<= 1) pp += __shfl_xor(pp, d, 64);
            if (lane == 0) out[v] = pp + bc[0];
        }
    }
}

extern "C" void kernel_launch(void* const* d_in, const int* in_sizes, int n_in,
                              void* d_out, int out_size, void* d_ws, size_t ws_size,
                              hipStream_t stream) {
    const float* x   = (const float*)d_in[0];
    const int*   ei  = (const int*)d_in[1];
    const float* Wl0 = (const float*)d_in[2];
    const float* Wr0 = (const float*)d_in[3];
    const float* b0  = (const float*)d_in[4];
    const float* Wl1 = (const float*)d_in[5];
    const float* Wr1 = (const float*)d_in[6];
    const float* b1  = (const float*)d_in[7];
    const float* Wl2 = (const float*)d_in[8];
    const float* Wr2 = (const float*)d_in[9];
    const float* b2  = (const float*)d_in[10];
    const float* Wc  = (const float*)d_in[11];
    const float* bc  = (const float*)d_in[12];
    float* out = (float*)d_out;

    const int N = NN;
    const int E = in_sizes[1] / 2;
    const int* src = ei;
    const int* dst = ei + E;
    const int M = NBK * HB;            // 400128 scan entries

    char* ws = (char*)d_ws;
    const size_t KB = 1 << 10;
    const size_t MB = 1 << 20;
    int*      ghT  = (int*)(ws + 0);             // [HB][NBK] counts, 1.6 MB
    int*      gh2T = (int*)(ws + 2 * MB);        // [HB][NBK] local offs, 1.6 MB
    int*      ghm  = (int*)(ws + 4 * MB);        // [NBK][HB] -> scanned prefix
    int*      gh2m = (int*)(ws + 6 * MB);        // [NBK][HB] local offs
    int*      off  = (int*)(ws + 8 * MB);        // 400 KB
    float*    inv  = (float*)(ws + 8 * MB + 512 * KB);
    int*      segs = (int*)(ws + 9 * MB);        // 32 KB
    unsigned* pair = (unsigned*)(ws + 10 * MB);  // 12.8e6 B, block-major
    int*      adj  = (int*)(ws + 23 * MB);       // 12.8e6 B CSR adjacency
    unsigned* g0 = (unsigned*)(ws + 36 * MB);    // bf16x2, 12.8e6 B
    float*    r0 = (float*)(ws + 49 * MB);       // fp32 25.6e6 B; h1 ALIASES r0
    float*    h1 = r0;
    unsigned* g1 = (unsigned*)(ws + 10 * MB);    // 6.4e6 (pair dead)
    float*    r1 = (float*)(ws + 36 * MB);       // 12.8e6 (g0 dead); h2 ALIASES r1
    float*    h2 = r1;
    unsigned* g2 = (unsigned*)(ws + 17 * MB);    // 3.2e6
    float*    r2 = (float*)(ws + 10 * MB);       // 6.4e6 (g1 dead after agg1)

    // ---- counting-sort CSR build (no global atomics; block-major pair) ----
    part1_k<<<HB, 512, 0, stream>>>(src, dst, E, ghT, gh2T, pair);
    transpose_k<<<dim3((NBK + 31) / 32, HB / 32), 256, 0, stream>>>(ghT, gh2T, ghm, gh2m);
    scanA_k<<<SCB, 256, 0, stream>>>(ghm, M, segs);
    scanB_k<<<1, 1024, 0, stream>>>(segs);
    scanC_k<<<SCB, 256, 0, stream>>>(ghm, M, segs);
    sort_bucket_k<<<NBK, HB, 0, stream>>>(pair, ghm, gh2m, adj, off, inv, N, E);

    // ---- layer 0: 64 -> 64 ----
    transform2_k<64, 64><<<(N / 2 * 32 + 255) / 256, 256, 0, stream>>>(x, Wl0, Wr0, b0, g0, (float2*)r0, N);
    agg_k<64, 4, 0><<<(N + 3) / 4, 256, 0, stream>>>(g0, off, adj, inv, r0, nullptr, nullptr, h1, N);

    // ---- layer 1: 64 -> 32 ----
    transform2_k<64, 32><<<(N / 2 * 16 + 255) / 256, 256, 0, stream>>>(h1, Wl1, Wr1, b1, g1, (float2*)r1, N);
    agg_k<32, 4, 0><<<(N + 3) / 4, 256, 0, stream>>>(g1, off, adj, inv, r1, nullptr, nullptr, h2, N);

    // ---- layer 2: 32 -> 16, head 16 -> 1 fused ----
    transform2_k<32, 16><<<(N / 2 * 8 + 255) / 256, 256, 0, stream>>>(h2, Wl2, Wr2, b2, g2, (float2*)r2, N);
    agg_k<16, 4, 1><<<(N + 3) / 4, 256, 0, stream>>>(g2, off, adj, inv, r2, Wc, bc, out, N);
}

// Round 10
// 434.345 us; speedup vs baseline: 1.1317x; 1.1317x over previous
//
#include <hip/hip_runtime.h>

// GraphSAGE: 3x SAGEConv(mean) + linear head.
// N=100000 nodes, E=3200000 edges, dims 64 -> 64 -> 32 -> 16 -> 1.
// Round 10 = round 9 with 512-node buckets (BSH 9) so regroup slices are
// line-granular (~64 edges = 256 B; round-9's 32 B slices caused 10x read
// amp in sort_bucket: FETCH 245 MB). Transpose + 3-phase scan replaced by
// a single tiny bucket-base scan (bsum_k). Build = 3 kernels:
//  part1_k: block-major pair (contiguous block-exclusive writes, amp~1),
//           c-major per-(chunk,bucket) count/offset tables.
//  bsum_k:  per-bucket totals + exclusive scan -> adj bases (1 block).
//  sort2_k: per-bucket counting sort (one 256-B slice per thread, 2 passes,
//           2nd pass L2-hot) -> per-node CSR adj/off/inv.
// Layers unchanged: transform2 (g=h@Wl bf16, r=h@Wr+b), PULL agg_k.
//  - round-5 lesson: don't scatter-accumulate; PULL per node.
//  - round-4 lesson: no global atomics; block-exclusive write regions only.
// agg-linearity: mean(h[src]) @ Wl == mean((h@Wl)[src]) -> transform first.

#define NN 100000
#define BSH 9                       // bucket = dst >> 9 (512 nodes)
#define NBK ((NN + 511) >> 9)       // 196 buckets
#define HB 256                      // partition chunks / slices per bucket
#define SRCMASK 0x1FFFF             // 17 bits, N=100000 < 2^17
#define DLSH 17                     // dl = dst & 511 packed at bit 17

__device__ __forceinline__ unsigned f2bf(float f) {   // RNE fp32->bf16
    unsigned u = __float_as_uint(f);
    u += 0x7fffu + ((u >> 16) & 1u);
    return u >> 16;
}
__device__ __forceinline__ float bflo(unsigned u) { return __uint_as_float(u << 16); }
__device__ __forceinline__ float bfhi(unsigned u) { return __uint_as_float(u & 0xffff0000u); }

// ---- fused: per-chunk bucket histogram + local scan + grouped place ----
// Block c owns edges [b0,e0) and pair slots [b0,e0) (block-major => all
// pair writes contiguous & block-exclusive). Tables written c-major.
__global__ void part1_k(const int* __restrict__ src, const int* __restrict__ dst,
                        int E, int* __restrict__ gcnt, int* __restrict__ goff,
                        unsigned* __restrict__ pair) {
    __shared__ int lh[NBK];
    __shared__ int part[512];
    int c = blockIdx.x, tid = threadIdx.x;
    int chunk = (E + HB - 1) / HB;
    int b0 = c * chunk, e0 = min(b0 + chunk, E);
    if (tid < NBK) lh[tid] = 0;
    __syncthreads();
    for (int e = b0 + tid; e < e0; e += 512) atomicAdd(&lh[dst[e] >> BSH], 1);
    __syncthreads();
    int cnt = (tid < NBK) ? lh[tid] : 0;
    part[tid] = cnt;
    __syncthreads();
    for (int d = 1; d < 512; d <<= 1) {
        int t = (tid >= d) ? part[tid - d] : 0;
        __syncthreads();
        part[tid] += t;
        __syncthreads();
    }
    int run = (tid == 0) ? 0 : part[tid - 1];
    if (tid < NBK) {
        gcnt[(size_t)c * NBK + tid] = cnt;   // counts, c-major (contiguous)
        goff[(size_t)c * NBK + tid] = run;   // local offsets, c-major
        lh[tid] = run;                       // becomes cursor
    }
    __syncthreads();
    for (int e = b0 + tid; e < e0; e += 512) {
        int dv = dst[e], sv = src[e];
        int p = b0 + atomicAdd(&lh[dv >> BSH], 1);
        pair[p] = (unsigned)sv | ((unsigned)(dv & 511) << DLSH);
    }
}

// ---- per-bucket totals + exclusive scan -> adj base per bucket ----
// One block; at fixed c the 196 lanes read contiguous ints (coalesced).
__global__ void bsum_k(const int* __restrict__ gcnt, int* __restrict__ bb, int E) {
    __shared__ int part[256];
    int tid = threadIdx.x;
    int s = 0;
    if (tid < NBK)
        for (int c = 0; c < HB; ++c) s += gcnt[(size_t)c * NBK + tid];
    part[tid] = s;
    __syncthreads();
    for (int d = 1; d < 256; d <<= 1) {
        int t = (tid >= d) ? part[tid - d] : 0;
        __syncthreads();
        part[tid] += t;
        __syncthreads();
    }
    if (tid < NBK) bb[tid] = part[tid] - s;   // exclusive prefix
    if (tid == 0) bb[NBK] = E;
}

// ---- per-bucket counting sort -> per-node CSR (adj, off, inv) ----
// One block per bucket (512 nodes); thread c owns slice (bucket, chunk c),
// ~64 contiguous edges (256 B, line-granular). Pass 2 re-reads the block's
// ~64 KB working set from L2. adj writes block-exclusive contiguous.
__global__ void sort2_k(const unsigned* __restrict__ pair, const int* __restrict__ goff,
                        const int* __restrict__ bb, int* __restrict__ adj,
                        int* __restrict__ off, float* __restrict__ inv, int N, int E) {
    __shared__ int sls[HB], sle[HB];
    __shared__ int lcnt[512], lcur[512];
    __shared__ int part[256];
    int b = blockIdx.x, tid = threadIdx.x;   // blockDim == HB == 256
    int chunk = (E + HB - 1) / HB;
    int b0c = tid * chunk, e0c = min(b0c + chunk, E);
    sls[tid] = b0c + goff[(size_t)tid * NBK + b];
    sle[tid] = (b + 1 < NBK) ? (b0c + goff[(size_t)tid * NBK + b + 1]) : e0c;
    lcnt[tid] = 0; lcnt[tid + 256] = 0;
    __syncthreads();
    for (int i = sls[tid]; i < sle[tid]; ++i)
        atomicAdd(&lcnt[pair[i] >> DLSH], 1);
    __syncthreads();
    int c0 = lcnt[2 * tid], c1 = lcnt[2 * tid + 1];
    part[tid] = c0 + c1;
    __syncthreads();
    for (int d = 1; d < 256; d <<= 1) {
        int t = (tid >= d) ? part[tid - d] : 0;
        __syncthreads();
        part[tid] += t;
        __syncthreads();
    }
    int run = (tid == 0) ? 0 : part[tid - 1];
    int base = bb[b];
    int v0 = b << BSH;
    int vg0 = v0 + 2 * tid, vg1 = v0 + 2 * tid + 1;
    if (vg0 < N) { off[vg0] = base + run;      inv[vg0] = 1.f / (float)max(c0, 1); }
    if (vg1 < N) { off[vg1] = base + run + c0; inv[vg1] = 1.f / (float)max(c1, 1); }
    lcur[2 * tid] = base + run;
    lcur[2 * tid + 1] = base + run + c0;
    if (b == NBK - 1 && tid == 0) off[N] = E;
    __syncthreads();
    for (int i = sls[tid]; i < sle[tid]; ++i) {
        unsigned u = pair[i];
        int p = atomicAdd(&lcur[u >> DLSH], 1);
        adj[p] = u & SRCMASK;
    }
}

// ---- transform2: g = h@Wl (bf16 packed), r = h@Wr + b (fp32) ----
// node-paired (2 nodes, 2 channels per thread) so LDS-read:FMA <= 2B/FMA.
template <int DIN, int DOUT>
__global__ void transform2_k(const float* __restrict__ h,
                             const float* __restrict__ Wl, const float* __restrict__ Wr,
                             const float* __restrict__ bias,
                             unsigned* __restrict__ g, float2* __restrict__ r, int N) {
    constexpr int JP = DOUT / 2;
    __shared__ float2 sWl[DIN * JP];
    __shared__ float2 sWr[DIN * JP];
    __shared__ float2 sb[JP];
    const float2* Wl2 = (const float2*)Wl;
    const float2* Wr2 = (const float2*)Wr;
    for (int i = threadIdx.x; i < DIN * JP; i += blockDim.x) { sWl[i] = Wl2[i]; sWr[i] = Wr2[i]; }
    if (threadIdx.x < JP) sb[threadIdx.x] = ((const float2*)bias)[threadIdx.x];
    __syncthreads();
    int idx = blockIdx.x * blockDim.x + threadIdx.x;
    int NP = N / 2;                    // N even
    if (idx >= NP * JP) return;
    int p = idx / JP, jp = idx % JP;
    int v0 = 2 * p, v1 = v0 + 1;
    const float* h0 = h + (size_t)v0 * DIN;
    const float* h1 = h + (size_t)v1 * DIN;
    float gl0x = 0, gl0y = 0, gl1x = 0, gl1y = 0;
    float gr0x = 0, gr0y = 0, gr1x = 0, gr1y = 0;
#pragma unroll
    for (int k = 0; k < DIN; ++k) {
        float2 wl = sWl[k * JP + jp];
        float2 wr = sWr[k * JP + jp];
        float a0 = h0[k], a1 = h1[k];
        gl0x = fmaf(a0, wl.x, gl0x); gl0y = fmaf(a0, wl.y, gl0y);
        gl1x = fmaf(a1, wl.x, gl1x); gl1y = fmaf(a1, wl.y, gl1y);
        gr0x = fmaf(a0, wr.x, gr0x); gr0y = fmaf(a0, wr.y, gr0y);
        gr1x = fmaf(a1, wr.x, gr1x); gr1y = fmaf(a1, wr.y, gr1y);
    }
    float2 bb = sb[jp];
    g[(size_t)v0 * JP + jp] = f2bf(gl0x) | (f2bf(gl0y) << 16);
    g[(size_t)v1 * JP + jp] = f2bf(gl1x) | (f2bf(gl1y) << 16);
    r[(size_t)v0 * JP + jp] = make_float2(gr0x + bb.x, gr0y + bb.y);
    r[(size_t)v1 * JP + jp] = make_float2(gr1x + bb.x, gr1y + bb.y);
}

// ---- agg: out = relu( mean-gather(g_bf16) + r ); optional fused head ----
// One wave per dst node (PULL). Q8 = DOUT/8 lanes x uint4 (8 bf16) per row;
// EPT = 64/Q8 edge groups, 4x unroll. NOTE: out may alias r (in-place).
template <int DOUT, int WAVES, int HEAD>
__global__ void agg_k(const unsigned* __restrict__ g, const int* __restrict__ off,
                      const int* __restrict__ adj, const float* __restrict__ invc,
                      const float* r, const float* __restrict__ Wc,
                      const float* __restrict__ bc, float* out, int N) {
    constexpr int Q8 = DOUT / 8;
    constexpr int EPT = 64 / Q8;
    __shared__ float sagg[WAVES][DOUT];
    int wid = threadIdx.x >> 6, lane = threadIdx.x & 63;
    int v = blockIdx.x * WAVES + wid;
    bool active = v < N;
    int q = lane & (Q8 - 1);
    int eg = lane / Q8;
    float acc[8] = {0, 0, 0, 0, 0, 0, 0, 0};
#define ACCU(U) do { \
        acc[0] += bflo(U.x); acc[1] += bfhi(U.x); \
        acc[2] += bflo(U.y); acc[3] += bfhi(U.y); \
        acc[4] += bflo(U.z); acc[5] += bfhi(U.z); \
        acc[6] += bflo(U.w); acc[7] += bfhi(U.w); } while (0)
    if (active) {
        int beg = off[v], end = off[v + 1];
        const uint4* g4 = (const uint4*)g;   // row = Q8 uint4s
        int i = beg + eg;
        for (; i + 3 * EPT < end; i += 4 * EPT) {
            int s0 = adj[i], s1 = adj[i + EPT], s2 = adj[i + 2 * EPT], s3 = adj[i + 3 * EPT];
            uint4 u0 = g4[(size_t)s0 * Q8 + q];
            uint4 u1 = g4[(size_t)s1 * Q8 + q];
            uint4 u2 = g4[(size_t)s2 * Q8 + q];
            uint4 u3 = g4[(size_t)s3 * Q8 + q];
            ACCU(u0); ACCU(u1); ACCU(u2); ACCU(u3);
        }
        for (; i < end; i += EPT) {
            int sv = adj[i];
            uint4 u = g4[(size_t)sv * Q8 + q];
            ACCU(u);
        }
#pragma unroll
        for (int d = Q8; d < 64; d <<= 1)
#pragma unroll
            for (int c = 0; c < 8; ++c) acc[c] += __shfl_xor(acc[c], d, 64);
        if (eg == 0) {
            float4* sp = (float4*)&sagg[wid][q * 8];
            sp[0] = make_float4(acc[0], acc[1], acc[2], acc[3]);
            sp[1] = make_float4(acc[4], acc[5], acc[6], acc[7]);
        }
    }
#undef ACCU
    __syncthreads();
    if (active && lane < DOUT) {
        float iv = invc[v];
        float val = fmaxf(fmaf(sagg[wid][lane], iv, r[(size_t)v * DOUT + lane]), 0.f);
        if (!HEAD) {
            out[(size_t)v * DOUT + lane] = val;   // may alias r: read-before-write per thread
        } else {
            float pp = val * Wc[lane];
#pragma unroll
            for (int d = 1; d < 16; d <<= 1) pp += __shfl_xor(pp, d, 64);
            if (lane == 0) out[v] = pp + bc[0];
        }
    }
}

extern "C" void kernel_launch(void* const* d_in, const int* in_sizes, int n_in,
                              void* d_out, int out_size, void* d_ws, size_t ws_size,
                              hipStream_t stream) {
    const float* x   = (const float*)d_in[0];
    const int*   ei  = (const int*)d_in[1];
    const float* Wl0 = (const float*)d_in[2];
    const float* Wr0 = (const float*)d_in[3];
    const float* b0  = (const float*)d_in[4];
    const float* Wl1 = (const float*)d_in[5];
    const float* Wr1 = (const float*)d_in[6];
    const float* b1  = (const float*)d_in[7];
    const float* Wl2 = (const float*)d_in[8];
    const float* Wr2 = (const float*)d_in[9];
    const float* b2  = (const float*)d_in[10];
    const float* Wc  = (const float*)d_in[11];
    const float* bc  = (const float*)d_in[12];
    float* out = (float*)d_out;

    const int N = NN;
    const int E = in_sizes[1] / 2;
    const int* src = ei;
    const int* dst = ei + E;

    char* ws = (char*)d_ws;
    const size_t MB = 1 << 20;
    int*      gcnt = (int*)(ws + 0);             // [HB][NBK] counts, 200 KB
    int*      goff = (int*)(ws + 1 * MB);        // [HB][NBK] local offs, 200 KB
    int*      bb   = (int*)(ws + 2 * MB);        // (NBK+1) bucket bases
    int*      off  = (int*)(ws + 3 * MB);        // 400 KB + 4
    float*    inv  = (float*)(ws + 3 * MB + 512 * 1024);
    unsigned* pair = (unsigned*)(ws + 4 * MB);   // 12.8e6 B, block-major
    int*      adj  = (int*)(ws + 17 * MB);       // 12.8e6 B CSR adjacency
    unsigned* g0 = (unsigned*)(ws + 30 * MB);    // bf16x2, 12.8e6 B
    float*    r0 = (float*)(ws + 43 * MB);       // fp32 25.6e6 B; h1 ALIASES r0
    float*    h1 = r0;
    unsigned* g1 = (unsigned*)(ws + 4 * MB);     // 6.4e6 (pair dead)
    float*    r1 = (float*)(ws + 30 * MB);       // 12.8e6 (g0 dead); h2 ALIASES r1
    float*    h2 = r1;
    unsigned* g2 = (unsigned*)(ws + 11 * MB);    // 3.2e6 (pair region, g1 untouched)
    float*    r2 = (float*)(ws + 43 * MB);       // 6.4e6 (h1 dead after transform L1)

    // ---- counting-sort CSR build: 3 kernels, no global atomics ----
    part1_k<<<HB, 512, 0, stream>>>(src, dst, E, gcnt, goff, pair);
    bsum_k<<<1, 256, 0, stream>>>(gcnt, bb, E);
    sort2_k<<<NBK, HB, 0, stream>>>(pair, goff, bb, adj, off, inv, N, E);

    // ---- layer 0: 64 -> 64 ----
    transform2_k<64, 64><<<(N / 2 * 32 + 255) / 256, 256, 0, stream>>>(x, Wl0, Wr0, b0, g0, (float2*)r0, N);
    agg_k<64, 4, 0><<<(N + 3) / 4, 256, 0, stream>>>(g0, off, adj, inv, r0, nullptr, nullptr, h1, N);

    // ---- layer 1: 64 -> 32 ----
    transform2_k<64, 32><<<(N / 2 * 16 + 255) / 256, 256, 0, stream>>>(h1, Wl1, Wr1, b1, g1, (float2*)r1, N);
    agg_k<32, 4, 0><<<(N + 3) / 4, 256, 0, stream>>>(g1, off, adj, inv, r1, nullptr, nullptr, h2, N);

    // ---- layer 2: 32 -> 16, head 16 -> 1 fused ----
    transform2_k<32, 16><<<(N / 2 * 8 + 255) / 256, 256, 0, stream>>>(h2, Wl2, Wr2, b2, g2, (float2*)r2, N);
    agg_k<16, 4, 1><<<(N + 3) / 4, 256, 0, stream>>>(g2, off, adj, inv, r2, Wc, bc, out, N);
}

// Round 11
// 405.443 us; speedup vs baseline: 1.2124x; 1.0713x over previous
//
#include <hip/hip_runtime.h>

// GraphSAGE: 3x SAGEConv(mean) + linear head.
// N=100000 nodes, E=3200000 edges, dims 64 -> 64 -> 32 -> 16 -> 1.
// Round 11 = round 10 with ALL permutation writes staged in LDS and written
// out as full lines (round-10 lesson: scattered 4B stores dirty 32B sectors;
// L2 writes back unmerged -> sort2 had 10x write amp, 122MB for 12.8MB).
//  part1_k: hist + scan + place into LDS spair (block's exact 50KB chunk),
//           coalesced copy-out. pair block-major, write amp ~1.
//  bsum_k:  per-bucket totals + exclusive scan (1 block, 512 thr).
//  sort2_k: BSH 8 (256-node buckets, NBK 391) so a bucket's adjacency
//           (~8.2K edges) fits ladj[10240] in LDS; place at final local
//           positions in LDS, coalesced copy-out (overflow-> direct global,
//           never expected). One node per thread for count/scan.
// Layers unchanged: transform2 (g=h@Wl bf16, r=h@Wr+b fp32), PULL agg_k.
//  - round-5 lesson: don't scatter-accumulate features; PULL per node.
//  - round-4 lesson: no global atomics; block-exclusive write regions only.
// agg-linearity: mean(h[src]) @ Wl == mean((h@Wl)[src]) -> transform first.

#define NN 100000
#define BSH 8                       // bucket = dst >> 8 (256 nodes)
#define NBK ((NN + 255) >> 8)       // 391 buckets
#define HB 256                      // partition chunks / slices per bucket
#define SRCMASK 0x1FFFF             // 17 bits, N=100000 < 2^17
#define DLSH 17                     // dl = dst & 255 packed at bit 17
#define SPCAP 12500                 // = E/HB exactly (chunk size)
#define LADJ_CAP 10240              // bucket adjacency LDS capacity (mean 8184)

__device__ __forceinline__ unsigned f2bf(float f) {   // RNE fp32->bf16
    unsigned u = __float_as_uint(f);
    u += 0x7fffu + ((u >> 16) & 1u);
    return u >> 16;
}
__device__ __forceinline__ float bflo(unsigned u) { return __uint_as_float(u << 16); }
__device__ __forceinline__ float bfhi(unsigned u) { return __uint_as_float(u & 0xffff0000u); }

// ---- fused: per-chunk bucket histogram + local scan + LDS-staged place ----
// Block c owns edges [b0,e0) and pair slots [b0,e0). All global writes are
// contiguous block-exclusive full lines. Tables written c-major.
__global__ void part1_k(const int* __restrict__ src, const int* __restrict__ dst,
                        int E, int* __restrict__ gcnt, int* __restrict__ goff,
                        unsigned* __restrict__ pair) {
    __shared__ unsigned spair[SPCAP];
    __shared__ int lh[NBK];
    __shared__ int part[512];
    int c = blockIdx.x, tid = threadIdx.x;
    int chunk = (E + HB - 1) / HB;
    int b0 = c * chunk, e0 = min(b0 + chunk, E);
    int n = e0 - b0;
    if (tid < NBK) lh[tid] = 0;
    __syncthreads();
    for (int e = b0 + tid; e < e0; e += 512) atomicAdd(&lh[dst[e] >> BSH], 1);
    __syncthreads();
    int cnt = (tid < NBK) ? lh[tid] : 0;
    part[tid] = cnt;
    __syncthreads();
    for (int d = 1; d < 512; d <<= 1) {
        int t = (tid >= d) ? part[tid - d] : 0;
        __syncthreads();
        part[tid] += t;
        __syncthreads();
    }
    int run = (tid == 0) ? 0 : part[tid - 1];
    if (tid < NBK) {
        gcnt[(size_t)c * NBK + tid] = cnt;   // counts, c-major (contiguous)
        goff[(size_t)c * NBK + tid] = run;   // local offsets, c-major
        lh[tid] = run;                       // becomes cursor
    }
    __syncthreads();
    for (int e = b0 + tid; e < e0; e += 512) {
        int dv = dst[e], sv = src[e];
        int p = atomicAdd(&lh[dv >> BSH], 1);          // bucket-grouped local pos
        spair[p] = (unsigned)sv | ((unsigned)(dv & 255) << DLSH);
    }
    __syncthreads();
    for (int i = tid; i < n; i += 512) pair[b0 + i] = spair[i];   // full-line writes
}

// ---- per-bucket totals + exclusive scan -> adj base per bucket ----
__global__ void bsum_k(const int* __restrict__ gcnt, int* __restrict__ bb, int E) {
    __shared__ int part[512];
    int tid = threadIdx.x;
    int s = 0;
    if (tid < NBK)
        for (int c = 0; c < HB; ++c) s += gcnt[(size_t)c * NBK + tid];
    part[tid] = s;
    __syncthreads();
    for (int d = 1; d < 512; d <<= 1) {
        int t = (tid >= d) ? part[tid - d] : 0;
        __syncthreads();
        part[tid] += t;
        __syncthreads();
    }
    if (tid < NBK) bb[tid] = part[tid] - s;   // exclusive prefix
    if (tid == 0) bb[NBK] = E;
}

// ---- per-bucket counting sort -> per-node CSR (adj, off, inv) ----
// One block per 256-node bucket; thread c owns slice (bucket, chunk c)
// (~32 contiguous edges). Place at final local positions in LDS ladj,
// then coalesced full-line copy-out. Pass 2 re-reads pair from L2.
__global__ void sort2_k(const unsigned* __restrict__ pair, const int* __restrict__ goff,
                        const int* __restrict__ bb, int* __restrict__ adj,
                        int* __restrict__ off, float* __restrict__ inv, int N, int E) {
    __shared__ int ladj[LADJ_CAP];
    __shared__ int sls[HB], sle[HB];
    __shared__ int lcur[256];
    __shared__ int part[256];
    int b = blockIdx.x, tid = threadIdx.x;   // blockDim == HB == 256
    int chunk = (E + HB - 1) / HB;
    int b0c = tid * chunk, e0c = min(b0c + chunk, E);
    int ls = b0c + goff[(size_t)tid * NBK + b];
    int le = (b + 1 < NBK) ? (b0c + goff[(size_t)tid * NBK + b + 1]) : e0c;
    sls[tid] = ls; sle[tid] = le;
    lcur[tid] = 0;
    __syncthreads();
    for (int i = ls; i < le; ++i)
        atomicAdd(&lcur[pair[i] >> DLSH], 1);          // count per node
    __syncthreads();
    int cn = lcur[tid];
    part[tid] = cn;
    __syncthreads();
    for (int d = 1; d < 256; d <<= 1) {
        int t = (tid >= d) ? part[tid - d] : 0;
        __syncthreads();
        part[tid] += t;
        __syncthreads();
    }
    int run = part[tid] - cn;                          // exclusive prefix
    int base = bb[b];
    int total = bb[b + 1] - base;
    int v = (b << BSH) + tid;
    if (v < N) { off[v] = base + run; inv[v] = 1.f / (float)max(cn, 1); }
    if (b == NBK - 1 && tid == 0) off[N] = E;
    lcur[tid] = run;                                   // becomes cursor
    __syncthreads();
    for (int i = sls[tid]; i < sle[tid]; ++i) {
        unsigned u = pair[i];
        int p = atomicAdd(&lcur[u >> DLSH], 1);
        int val = u & SRCMASK;
        if (p < LADJ_CAP) ladj[p] = val;               // staged (always, in practice)
        else adj[base + p] = val;                      // safety fallback
    }
    __syncthreads();
    int lim = min(total, LADJ_CAP);
    for (int i = tid; i < lim; i += 256) adj[base + i] = ladj[i];   // full-line writes
}

// ---- transform2: g = h@Wl (bf16 packed), r = h@Wr + b (fp32) ----
// node-paired (2 nodes, 2 channels per thread) so LDS-read:FMA <= 2B/FMA.
template <int DIN, int DOUT>
__global__ void transform2_k(const float* __restrict__ h,
                             const float* __restrict__ Wl, const float* __restrict__ Wr,
                             const float* __restrict__ bias,
                             unsigned* __restrict__ g, float2* __restrict__ r, int N) {
    constexpr int JP = DOUT / 2;
    __shared__ float2 sWl[DIN * JP];
    __shared__ float2 sWr[DIN * JP];
    __shared__ float2 sb[JP];
    const float2* Wl2 = (const float2*)Wl;
    const float2* Wr2 = (const float2*)Wr;
    for (int i = threadIdx.x; i < DIN * JP; i += blockDim.x) { sWl[i] = Wl2[i]; sWr[i] = Wr2[i]; }
    if (threadIdx.x < JP) sb[threadIdx.x] = ((const float2*)bias)[threadIdx.x];
    __syncthreads();
    int idx = blockIdx.x * blockDim.x + threadIdx.x;
    int NP = N / 2;                    // N even
    if (idx >= NP * JP) return;
    int p = idx / JP, jp = idx % JP;
    int v0 = 2 * p, v1 = v0 + 1;
    const float* h0 = h + (size_t)v0 * DIN;
    const float* h1 = h + (size_t)v1 * DIN;
    float gl0x = 0, gl0y = 0, gl1x = 0, gl1y = 0;
    float gr0x = 0, gr0y = 0, gr1x = 0, gr1y = 0;
#pragma unroll
    for (int k = 0; k < DIN; ++k) {
        float2 wl = sWl[k * JP + jp];
        float2 wr = sWr[k * JP + jp];
        float a0 = h0[k], a1 = h1[k];
        gl0x = fmaf(a0, wl.x, gl0x); gl0y = fmaf(a0, wl.y, gl0y);
        gl1x = fmaf(a1, wl.x, gl1x); gl1y = fmaf(a1, wl.y, gl1y);
        gr0x = fmaf(a0, wr.x, gr0x); gr0y = fmaf(a0, wr.y, gr0y);
        gr1x = fmaf(a1, wr.x, gr1x); gr1y = fmaf(a1, wr.y, gr1y);
    }
    float2 bb = sb[jp];
    g[(size_t)v0 * JP + jp] = f2bf(gl0x) | (f2bf(gl0y) << 16);
    g[(size_t)v1 * JP + jp] = f2bf(gl1x) | (f2bf(gl1y) << 16);
    r[(size_t)v0 * JP + jp] = make_float2(gr0x + bb.x, gr0y + bb.y);
    r[(size_t)v1 * JP + jp] = make_float2(gr1x + bb.x, gr1y + bb.y);
}

// ---- agg: out = relu( mean-gather(g_bf16) + r ); optional fused head ----
// One wave per dst node (PULL). Q8 = DOUT/8 lanes x uint4 (8 bf16) per row;
// EPT = 64/Q8 edge groups, 4x unroll. NOTE: out may alias r (in-place).
template <int DOUT, int WAVES, int HEAD>
__global__ void agg_k(const unsigned* __restrict__ g, const int* __restrict__ off,
                      const int* __restrict__ adj, const float* __restrict__ invc,
                      const float* r, const float* __restrict__ Wc,
                      const float* __restrict__ bc, float* out, int N) {
    constexpr int Q8 = DOUT / 8;
    constexpr int EPT = 64 / Q8;
    __shared__ float sagg[WAVES][DOUT];
    int wid = threadIdx.x >> 6, lane = threadIdx.x & 63;
    int v = blockIdx.x * WAVES + wid;
    bool active = v < N;
    int q = lane & (Q8 - 1);
    int eg = lane / Q8;
    float acc[8] = {0, 0, 0, 0, 0, 0, 0, 0};
#define ACCU(U) do { \
        acc[0] += bflo(U.x); acc[1] += bfhi(U.x); \
        acc[2] += bflo(U.y); acc[3] += bfhi(U.y); \
        acc[4] += bflo(U.z); acc[5] += bfhi(U.z); \
        acc[6] += bflo(U.w); acc[7] += bfhi(U.w); } while (0)
    if (active) {
        int beg = off[v], end = off[v + 1];
        const uint4* g4 = (const uint4*)g;   // row = Q8 uint4s
        int i = beg + eg;
        for (; i + 3 * EPT < end; i += 4 * EPT) {
            int s0 = adj[i], s1 = adj[i + EPT], s2 = adj[i + 2 * EPT], s3 = adj[i + 3 * EPT];
            uint4 u0 = g4[(size_t)s0 * Q8 + q];
            uint4 u1 = g4[(size_t)s1 * Q8 + q];
            uint4 u2 = g4[(size_t)s2 * Q8 + q];
            uint4 u3 = g4[(size_t)s3 * Q8 + q];
            ACCU(u0); ACCU(u1); ACCU(u2); ACCU(u3);
        }
        for (; i < end; i += EPT) {
            int sv = adj[i];
            uint4 u = g4[(size_t)sv * Q8 + q];
            ACCU(u);
        }
#pragma unroll
        for (int d = Q8; d < 64; d <<= 1)
#pragma unroll
            for (int c = 0; c < 8; ++c) acc[c] += __shfl_xor(acc[c], d, 64);
        if (eg == 0) {
            float4* sp = (float4*)&sagg[wid][q * 8];
            sp[0] = make_float4(acc[0], acc[1], acc[2], acc[3]);
            sp[1] = make_float4(acc[4], acc[5], acc[6], acc[7]);
        }
    }
#undef ACCU
    __syncthreads();
    if (active && lane < DOUT) {
        float iv = invc[v];
        float val = fmaxf(fmaf(sagg[wid][lane], iv, r[(size_t)v * DOUT + lane]), 0.f);
        if (!HEAD) {
            out[(size_t)v * DOUT + lane] = val;   // may alias r: read-before-write per thread
        } else {
            float pp = val * Wc[lane];
#pragma unroll
            for (int d = 1; d < 16; d <<= 1) pp += __shfl_xor(pp, d, 64);
            if (lane == 0) out[v] = pp + bc[0];
        }
    }
}

extern "C" void kernel_launch(void* const* d_in, const int* in_sizes, int n_in,
                              void* d_out, int out_size, void* d_ws, size_t ws_size,
                              hipStream_t stream) {
    const float* x   = (const float*)d_in[0];
    const int*   ei  = (const int*)d_in[1];
    const float* Wl0 = (const float*)d_in[2];
    const float* Wr0 = (const float*)d_in[3];
    const float* b0  = (const float*)d_in[4];
    const float* Wl1 = (const float*)d_in[5];
    const float* Wr1 = (const float*)d_in[6];
    const float* b1  = (const float*)d_in[7];
    const float* Wl2 = (const float*)d_in[8];
    const float* Wr2 = (const float*)d_in[9];
    const float* b2  = (const float*)d_in[10];
    const float* Wc  = (const float*)d_in[11];
    const float* bc  = (const float*)d_in[12];
    float* out = (float*)d_out;

    const int N = NN;
    const int E = in_sizes[1] / 2;
    const int* src = ei;
    const int* dst = ei + E;

    char* ws = (char*)d_ws;
    const size_t MB = 1 << 20;
    int*      gcnt = (int*)(ws + 0);             // [HB][NBK] counts, 400 KB
    int*      goff = (int*)(ws + 1 * MB);        // [HB][NBK] local offs, 400 KB
    int*      bb   = (int*)(ws + 2 * MB);        // (NBK+1) bucket bases
    int*      off  = (int*)(ws + 3 * MB);        // 400 KB + 4
    float*    inv  = (float*)(ws + 3 * MB + 512 * 1024);
    unsigned* pair = (unsigned*)(ws + 4 * MB);   // 12.8e6 B, block-major
    int*      adj  = (int*)(ws + 17 * MB);       // 12.8e6 B CSR adjacency
    unsigned* g0 = (unsigned*)(ws + 30 * MB);    // bf16x2, 12.8e6 B
    float*    r0 = (float*)(ws + 43 * MB);       // fp32 25.6e6 B; h1 ALIASES r0
    float*    h1 = r0;
    unsigned* g1 = (unsigned*)(ws + 4 * MB);     // 6.4e6 (pair dead)
    float*    r1 = (float*)(ws + 30 * MB);       // 12.8e6 (g0 dead); h2 ALIASES r1
    float*    h2 = r1;
    unsigned* g2 = (unsigned*)(ws + 11 * MB);    // 3.2e6 (pair region, g1 untouched)
    float*    r2 = (float*)(ws + 43 * MB);       // 6.4e6 (h1 dead after transform L1)

    // ---- counting-sort CSR build: 3 kernels, no global atomics,
    //      all global writes full-line via LDS staging ----
    part1_k<<<HB, 512, 0, stream>>>(src, dst, E, gcnt, goff, pair);
    bsum_k<<<1, 512, 0, stream>>>(gcnt, bb, E);
    sort2_k<<<NBK, HB, 0, stream>>>(pair, goff, bb, adj, off, inv, N, E);

    // ---- layer 0: 64 -> 64 ----
    transform2_k<64, 64><<<(N / 2 * 32 + 255) / 256, 256, 0, stream>>>(x, Wl0, Wr0, b0, g0, (float2*)r0, N);
    agg_k<64, 4, 0><<<(N + 3) / 4, 256, 0, stream>>>(g0, off, adj, inv, r0, nullptr, nullptr, h1, N);

    // ---- layer 1: 64 -> 32 ----
    transform2_k<64, 32><<<(N / 2 * 16 + 255) / 256, 256, 0, stream>>>(h1, Wl1, Wr1, b1, g1, (float2*)r1, N);
    agg_k<32, 4, 0><<<(N + 3) / 4, 256, 0, stream>>>(g1, off, adj, inv, r1, nullptr, nullptr, h2, N);

    // ---- layer 2: 32 -> 16, head 16 -> 1 fused ----
    transform2_k<32, 16><<<(N / 2 * 8 + 255) / 256, 256, 0, stream>>>(h2, Wl2, Wr2, b2, g2, (float2*)r2, N);
    agg_k<16, 4, 1><<<(N + 3) / 4, 256, 0, stream>>>(g2, off, adj, inv, r2, Wc, bc, out, N);
}